// Round 9
// baseline (165.441 us; speedup 1.0000x reference)
//
#include <hip/hip_runtime.h>
#include <hip/hip_fp16.h>

// GLOBE_61864708931733 — R9: shrink unified VGPR+AGPR footprint -> 3 waves/SIMD.
// R8 post-mortem: zero spills but occupancy pinned at 17.5% regardless of grid
// (R6 1024 blk == R8 2048 blk) -> residency capped by TOTAL unified register
// file (arch 112 + ~60-90 AGPR frags ≈ 200 -> 2 waves/SIMD). Trans-pipe floor
// ~20us + VALU ~11us; at 2 waves/SIMD issue idles 40% -> 70us.
// R9: drop W1 lo-split (-16 regs, -16 MFMA/chunk; +~0.1 absmax systematic,
// Wout keeps hi/lo), true live set ~155; __launch_bounds__(128,3) commits the
// allocator to <=170 total -> 3 waves/SIMD, 24 waves/CU. Rest identical to R8.

#define N_T 2048
#define N_S 512
#define BLK 128
#define SCALE 2.885390081777927f   // 2*log2(e)

typedef _Float16 f16;
typedef _Float16 f16x8 __attribute__((ext_vector_type(8)));
typedef _Float16 f16x4 __attribute__((ext_vector_type(4)));
typedef float f32x4 __attribute__((ext_vector_type(4)));
typedef unsigned short u16;
typedef unsigned int u32;

// Input x is already SCALE*y; tanh(y) = 1 - 2/(exp2(x)+1). Saturates exactly.
__device__ __forceinline__ float tanh_s(float x) {
    float e = __builtin_amdgcn_exp2f(x);
    return fmaf(-2.0f, __builtin_amdgcn_rcpf(e + 1.0f), 1.0f);
}

__device__ __forceinline__ f32x4 mfma16h(f16x8 a, f16x8 b, f32x4 c) {
    return __builtin_amdgcn_mfma_f32_16x16x32_f16(a, b, c, 0, 0, 0);
}

// ---- prep: pack A-frags (f16, frag-major) + scaled biases into d_ws ----
// ws layout: f16x8 frag[fid][lane], fid 0..23 (24*64*16 B = 24576 B), then
// f32 sbias[3][64] at float offset 6144. Frag table:
//   0..3 w1[mt] (plain) | 4..11 w2[ks*4+mt] | 12..19 w3[ks*4+mt]
//   20..21 woh[ks] | 22..23 wol[ks]
__global__ __launch_bounds__(256) void prep_kernel(
    const float* __restrict__ W1, const float* __restrict__ b1,
    const float* __restrict__ W2, const float* __restrict__ b2,
    const float* __restrict__ W3, const float* __restrict__ b3,
    const float* __restrict__ Wout, float* __restrict__ ws)
{
    const int tid = blockIdx.x * 256 + threadIdx.x;   // grid 8*256 = 2048
    const int fid = tid >> 6, lane = tid & 63;
    const int q = lane >> 4, l15 = lane & 15;

    if (fid < 24) {
        float x[8];
        bool lo = false;
        if (fid < 4) {                       // W1 plain (scaled), q==0 octet only
            const int mt = fid & 3;
            #pragma unroll
            for (int j = 0; j < 8; ++j)
                x[j] = (q == 0 && j < 7) ? W1[j * 64 + mt * 16 + l15] * SCALE : 0.f;
        } else if (fid < 12) {               // W2 plain (scaled)
            const int k = fid - 4, ks = k >> 2, mt = k & 3;
            #pragma unroll
            for (int j = 0; j < 8; ++j)
                x[j] = W2[(ks * 32 + q * 8 + j) * 64 + mt * 16 + l15] * SCALE;
        } else if (fid < 20) {               // W3 plain (scaled)
            const int k = fid - 12, ks = k >> 2, mt = k & 3;
            #pragma unroll
            for (int j = 0; j < 8; ++j)
                x[j] = W3[(ks * 32 + q * 8 + j) * 64 + mt * 16 + l15] * SCALE;
        } else {                             // Wout hi/lo (unscaled), rows<3 live
            const int ks = fid & 1;
            lo = (fid >= 22);
            #pragma unroll
            for (int j = 0; j < 8; ++j)
                x[j] = (l15 < 3) ? Wout[(ks * 32 + q * 8 + j) * 3 + l15] : 0.f;
        }
        f16x8 v;
        #pragma unroll
        for (int j = 0; j < 8; ++j) {
            const f16 h = (f16)x[j];
            v[j] = lo ? (f16)(x[j] - (float)h) : h;
        }
        *(f16x8*)((char*)ws + ((fid * 64 + lane) << 4)) = v;
    }

    if (tid >= 1792 && tid < 1984) {         // scaled biases
        const int Lb = (tid - 1792) >> 6, i = tid & 63;
        float bv;
        if (Lb == 0)      bv = b1[i];
        else if (Lb == 1) bv = b2[i];
        else              bv = b3[i];
        ws[6144 + (Lb * 64 + i)] = bv * SCALE;
    }
}

// One 64->64 tanh dense layer (in-place via per-wave LDS slab).
#define DENSE_LAYER(WARR, LIDX)                                                \
    {                                                                          \
        _Pragma("unroll")                                                      \
        for (int n4 = 0; n4 < 4; ++n4) {                                       \
            const int row = n4 * 16 + l15;                                     \
            const f16x8 bfa = *(const f16x8*)&hb[row][q * 8];                  \
            const f16x8 bfb = *(const f16x8*)&hb[row][32 + q * 8];             \
            f32x4 c[4];                                                        \
            _Pragma("unroll")                                                  \
            for (int mt = 0; mt < 4; ++mt) {                                   \
                const float4 b = wsB[(LIDX) * 16 + mt * 4 + q];                \
                c[mt] = (f32x4){b.x, b.y, b.z, b.w};                           \
            }                                                                  \
            _Pragma("unroll")                                                  \
            for (int mt = 0; mt < 4; ++mt)                                     \
                c[mt] = mfma16h(WARR[mt], bfa, c[mt]);                         \
            _Pragma("unroll")                                                  \
            for (int mt = 0; mt < 4; ++mt)                                     \
                c[mt] = mfma16h(WARR[4 + mt], bfb, c[mt]);                     \
            _Pragma("unroll")                                                  \
            for (int mt = 0; mt < 4; ++mt) {                                   \
                f16x4 o;                                                       \
                o[0] = (f16)tanh_s(c[mt][0]);                                  \
                o[1] = (f16)tanh_s(c[mt][1]);                                  \
                o[2] = (f16)tanh_s(c[mt][2]);                                  \
                o[3] = (f16)tanh_s(c[mt][3]);                                  \
                *(f16x4*)&hb[row][mt * 16 + q * 4] = o;                        \
            }                                                                  \
        }                                                                      \
    }

__global__ __launch_bounds__(BLK, 3) void globe_mfma(
    const float* __restrict__ pts, const float* __restrict__ ctr,
    const float* __restrict__ nrm, const float* __restrict__ areas,
    const float* __restrict__ rlen, const float* __restrict__ bout,
    const float* __restrict__ p_scale, const float* __restrict__ p_bias,
    const float* __restrict__ v_scale, const float* __restrict__ v_bias,
    const float* __restrict__ ws,
    float* __restrict__ out)
{
    __shared__ __align__(16) u16 hbuf[2][64][72];    // 18432 B
    __shared__ __align__(16) uint4 geomP[2][64];     // 2048 B -> total 20480 B

    const int tid  = threadIdx.x;
    const int lane = tid & 63;
    const int wv   = tid >> 6;
    const int l15  = lane & 15;
    const int q    = lane >> 4;
    const int t    = blockIdx.x;                     // both waves: same target

    const f16x8* __restrict__ wsF = (const f16x8*)ws;
    const float4* __restrict__ wsB = (const float4*)(ws + 6144);

    // ---- load pre-packed A-frags (24 coalesced 16B loads) ----
    f16x8 w1f[4], w2f[8], w3f[8], woh[2], wol[2];
    #pragma unroll
    for (int mt = 0; mt < 4; ++mt) w1f[mt] = wsF[(0 + mt) * 64 + lane];
    #pragma unroll
    for (int k = 0; k < 8; ++k)    w2f[k]  = wsF[(4 + k) * 64 + lane];
    #pragma unroll
    for (int k = 0; k < 8; ++k)    w3f[k]  = wsF[(12 + k) * 64 + lane];
    #pragma unroll
    for (int k = 0; k < 2; ++k)    woh[k]  = wsF[(20 + k) * 64 + lane];
    #pragma unroll
    for (int k = 0; k < 2; ++k)    wol[k]  = wsF[(22 + k) * 64 + lane];

    const float px = pts[3 * t + 0], py = pts[3 * t + 1], pz = pts[3 * t + 2];
    const float invL0 = __builtin_amdgcn_rcpf(rlen[0]);
    const float invL1 = __builtin_amdgcn_rcpf(rlen[1]);
    f32x4 co_init = (f32x4){0.f, 0.f, 0.f, 0.f};
    if (q == 0) { co_init[0] = bout[0]; co_init[1] = bout[1]; co_init[2] = bout[2]; }

    u16 (*hb)[72] = hbuf[wv];
    uint4* gp = geomP[wv];
    const f16x8 fzero = (f16x8){0, 0, 0, 0, 0, 0, 0, 0};
    float accp = 0.f, avx = 0.f, avy = 0.f, avz = 0.f;

    #pragma unroll 1
    for (int i = 0; i < 4; ++i) {
        const int s = (wv * 4 + i) * 64 + lane;
        // ---- per-pair geometry + features (lane = pair) ----
        const float cx = ctr[3 * s + 0], cy = ctr[3 * s + 1], cz = ctr[3 * s + 2];
        const float snx = nrm[3 * s + 0], sny = nrm[3 * s + 1], snz = nrm[3 * s + 2];
        const float ar = areas[s];
        const float rvx = px - cx, rvy = py - cy, rvz = pz - cz;
        const float r2 = rvx * rvx + rvy * rvy + rvz * rvz;
        const float r2e = r2 + 1e-8f;
        const float rinv = __builtin_amdgcn_rsqf(r2e);
        const float r = r2e * rinv;
        const float rhx = rvx * rinv, rhy = rvy * rinv, rhz = rvz * rinv;
        const float cth = rhx * snx + rhy * sny + rhz * snz;
        const float c2 = cth * cth;
        const float decay = ar * __builtin_amdgcn_rcpf(r2 + 1.0f);
        {
            f16x8 fv;
            fv[0] = (f16)(__builtin_amdgcn_rcpf(fmaf(r, invL0, 1.0f)));
            fv[1] = (f16)(__builtin_amdgcn_rcpf(fmaf(r, invL1, 1.0f)));
            fv[2] = (f16)1.0f;
            fv[3] = (f16)cth;
            fv[4] = (f16)fmaf(1.5f, c2, -0.5f);
            fv[5] = (f16)(cth * fmaf(2.5f, c2, -1.5f));
            fv[6] = (f16)__logf(ar);
            fv[7] = (f16)0.0f;
            *(f16x8*)&hb[lane][0] = fv;
        }
        {
            uint4 g;
            g.x = __builtin_bit_cast(u32, decay);
            g.y = __builtin_bit_cast(u32, __floats2half2_rn(rhx, rhy));
            g.z = __builtin_bit_cast(u32, __floats2half2_rn(rhz, snx));
            g.w = __builtin_bit_cast(u32, __floats2half2_rn(sny, snz));
            gp[lane] = g;
        }

        // ---- layer 1: K=32 with only k=0..7 live (q>0 contributes zeros) ----
        #pragma unroll
        for (int n4 = 0; n4 < 4; ++n4) {
            const int row = n4 * 16 + l15;
            const f16x8 lv = *(const f16x8*)&hb[row][0];
            const f16x8 bf = (q == 0) ? lv : fzero;   // value select
            f32x4 c[4];
            #pragma unroll
            for (int mt = 0; mt < 4; ++mt) {
                const float4 b = wsB[mt * 4 + q];
                c[mt] = (f32x4){b.x, b.y, b.z, b.w};
            }
            #pragma unroll
            for (int mt = 0; mt < 4; ++mt) c[mt] = mfma16h(w1f[mt], bf, c[mt]);
            #pragma unroll
            for (int mt = 0; mt < 4; ++mt) {
                f16x4 o;
                o[0] = (f16)tanh_s(c[mt][0]);
                o[1] = (f16)tanh_s(c[mt][1]);
                o[2] = (f16)tanh_s(c[mt][2]);
                o[3] = (f16)tanh_s(c[mt][3]);
                *(f16x4*)&hb[row][mt * 16 + q * 4] = o;
            }
        }

        // ---- layers 2 & 3 ----
        DENSE_LAYER(w2f, 1)
        DENSE_LAYER(w3f, 2)

        // ---- output layer + decay-weighted accumulation ----
        #pragma unroll
        for (int n4 = 0; n4 < 4; ++n4) {
            const int row = n4 * 16 + l15;
            const f16x8 bfa = *(const f16x8*)&hb[row][q * 8];
            const f16x8 bfb = *(const f16x8*)&hb[row][32 + q * 8];
            f32x4 co = co_init;
            co = mfma16h(woh[0], bfa, co);
            co = mfma16h(wol[0], bfa, co);
            co = mfma16h(woh[1], bfb, co);
            co = mfma16h(wol[1], bfb, co);
            if (q == 0) {   // C rows 0..2 = out channels, live in lanes 0..15
                const uint4 g = gp[row];
                const float d = __builtin_bit_cast(float, g.x);
                const float2 rxy = __half22float2(__builtin_bit_cast(__half2, g.y));
                const float2 rzx = __half22float2(__builtin_bit_cast(__half2, g.z));
                const float2 nyz = __half22float2(__builtin_bit_cast(__half2, g.w));
                const float o0 = co[0], o1 = co[1], o2 = co[2];
                accp = fmaf(o0, d, accp);
                avx  = fmaf(fmaf(o1, rxy.x, o2 * rzx.y), d, avx);
                avy  = fmaf(fmaf(o1, rxy.y, o2 * nyz.x), d, avy);
                avz  = fmaf(fmaf(o1, rzx.x, o2 * nyz.y), d, avz);
            }
        }
    }

    // ---- reduce across the 16 accumulating lanes ----
    #pragma unroll
    for (int off = 8; off > 0; off >>= 1) {
        accp += __shfl_down(accp, off);
        avx  += __shfl_down(avx,  off);
        avy  += __shfl_down(avy,  off);
        avz  += __shfl_down(avz,  off);
    }

    // ---- cross-wave combine via dead geom LDS ----
    __syncthreads();                         // all geom reads complete
    float* xr = (float*)&geomP[1][0];
    if (wv == 1 && lane == 0) {
        xr[0] = accp; xr[1] = avx; xr[2] = avy; xr[3] = avz;
    }
    __syncthreads();
    if (wv == 0 && lane == 0) {
        accp += xr[0]; avx += xr[1]; avy += xr[2]; avz += xr[3];
        const float ps = p_scale[0], pb = p_bias[0];
        const float vs = v_scale[0], vb = v_bias[0];
        out[4 * t + 0] = fmaf(accp, ps, pb);
        out[4 * t + 1] = fmaf(avx, vs, vb);
        out[4 * t + 2] = fmaf(avy, vs, vb);
        out[4 * t + 3] = fmaf(avz, vs, vb);
    }
}

extern "C" void kernel_launch(void* const* d_in, const int* in_sizes, int n_in,
                              void* d_out, int out_size, void* d_ws, size_t ws_size,
                              hipStream_t stream) {
    (void)in_sizes; (void)n_in; (void)ws_size; (void)out_size;
    const float* pts   = (const float*)d_in[0];
    const float* ctr   = (const float*)d_in[1];
    const float* nrm   = (const float*)d_in[2];
    const float* areas = (const float*)d_in[3];
    const float* rlen  = (const float*)d_in[4];
    const float* W1    = (const float*)d_in[5];
    const float* b1    = (const float*)d_in[6];
    const float* W2    = (const float*)d_in[7];
    const float* b2    = (const float*)d_in[8];
    const float* W3    = (const float*)d_in[9];
    const float* b3    = (const float*)d_in[10];
    const float* Wout  = (const float*)d_in[11];
    const float* bout  = (const float*)d_in[12];
    const float* ps    = (const float*)d_in[13];
    const float* pb    = (const float*)d_in[14];
    const float* vs    = (const float*)d_in[15];
    const float* vb    = (const float*)d_in[16];
    float* ws = (float*)d_ws;

    prep_kernel<<<8, 256, 0, stream>>>(W1, b1, W2, b2, W3, b3, Wout, ws);
    globe_mfma<<<N_T, BLK, 0, stream>>>(
        pts, ctr, nrm, areas, rlen, bout, ps, pb, vs, vb, ws, (float*)d_out);
}

// Round 11
// 144.819 us; speedup vs baseline: 1.1424x; 1.1424x over previous
//
#include <hip/hip_runtime.h>
#include <hip/hip_fp16.h>

// GLOBE_61864708931733 — R11: R10 (stream A-frags, demand ~105) + compile fix.
// R10 failed to compile: __builtin_amdgcn_cvt_pkrtz returns __fp16x2, not
// _Float16x2 -> bit_cast the builtin result to u32 directly.
// Theory unchanged: A-frags stream from d_ws per LAYER (<=32 transient regs),
// frag table replicated 4x (one copy per chunk) so loads are loop-variant and
// LICM can't hoist them into persistent registers. geom lives in hbuf's dead
// pad cols (72-wide rows, cols 64..71) -> LDS 18432 B -> 8 blocks/CU.
// W1/W2/W3 plain f16 prescaled by 2*log2e, Wout hi/lo. (128,2) bounds (the
// only spill-free profile); residency rises via lower alloc, not via hints.

#define N_T 2048
#define N_S 512
#define BLK 128
#define SCALE 2.885390081777927f   // 2*log2(e)

// d_ws layout: 4 copies (one per chunk), copy stride 6400 floats (25600 B):
//   [0..6143]   f16x8 frag[fid][lane], fid 0..23
//   [6144..6335] f32 sbias[3][64]
// Frag table: 0..3 w1[mt] | 4..11 w2[ks*4+mt] | 12..19 w3[ks*4+mt]
//             20..21 woh[ks] | 22..23 wol[ks]
#define CPY_F 6400     // floats per copy
#define CPY_V 1600     // f16x8 (16B) units per copy

typedef _Float16 f16;
typedef _Float16 f16x8 __attribute__((ext_vector_type(8)));
typedef float f32x4 __attribute__((ext_vector_type(4)));
typedef unsigned short u16;
typedef unsigned int u32;

// Input x is already SCALE*y; tanh(y) = 1 - 2/(exp2(x)+1). Saturates exactly.
__device__ __forceinline__ float tanh_s(float x) {
    float e = __builtin_amdgcn_exp2f(x);
    return fmaf(-2.0f, __builtin_amdgcn_rcpf(e + 1.0f), 1.0f);
}

__device__ __forceinline__ f32x4 mfma16h(f16x8 a, f16x8 b, f32x4 c) {
    return __builtin_amdgcn_mfma_f32_16x16x32_f16(a, b, c, 0, 0, 0);
}

// Pack 4 f32 -> 4 f16 (RTZ v_cvt_pkrtz) and store as one 8B LDS write.
__device__ __forceinline__ void store4h(u16* dst, float t0, float t1, float t2, float t3) {
    uint2 w;
    w.x = __builtin_bit_cast(u32, __builtin_amdgcn_cvt_pkrtz(t0, t1));
    w.y = __builtin_bit_cast(u32, __builtin_amdgcn_cvt_pkrtz(t2, t3));
    *(uint2*)dst = w;
}

__global__ __launch_bounds__(256) void prep_kernel(
    const float* __restrict__ W1, const float* __restrict__ b1,
    const float* __restrict__ W2, const float* __restrict__ b2,
    const float* __restrict__ W3, const float* __restrict__ b3,
    const float* __restrict__ Wout, float* __restrict__ ws)
{
    const int tid = blockIdx.x * 256 + threadIdx.x;   // grid 28*256 = 7168
    const int cpy = tid / 1792;                       // 4 copies
    const int rem = tid - cpy * 1792;                 // 28 fids * 64 lanes
    const int fid = rem >> 6, lane = rem & 63;
    const int q = lane >> 4, l15 = lane & 15;

    if (fid < 24) {
        float x[8];
        bool lo = false;
        if (fid < 4) {                       // W1 plain (scaled), q==0 octet only
            const int mt = fid & 3;
            #pragma unroll
            for (int j = 0; j < 8; ++j)
                x[j] = (q == 0 && j < 7) ? W1[j * 64 + mt * 16 + l15] * SCALE : 0.f;
        } else if (fid < 12) {               // W2 plain (scaled)
            const int k = fid - 4, ks = k >> 2, mt = k & 3;
            #pragma unroll
            for (int j = 0; j < 8; ++j)
                x[j] = W2[(ks * 32 + q * 8 + j) * 64 + mt * 16 + l15] * SCALE;
        } else if (fid < 20) {               // W3 plain (scaled)
            const int k = fid - 12, ks = k >> 2, mt = k & 3;
            #pragma unroll
            for (int j = 0; j < 8; ++j)
                x[j] = W3[(ks * 32 + q * 8 + j) * 64 + mt * 16 + l15] * SCALE;
        } else {                             // Wout hi/lo (unscaled), rows<3 live
            const int ks = fid & 1;
            lo = (fid >= 22);
            #pragma unroll
            for (int j = 0; j < 8; ++j)
                x[j] = (l15 < 3) ? Wout[(ks * 32 + q * 8 + j) * 3 + l15] : 0.f;
        }
        f16x8 v;
        #pragma unroll
        for (int j = 0; j < 8; ++j) {
            const f16 h = (f16)x[j];
            v[j] = lo ? (f16)(x[j] - (float)h) : h;
        }
        *(f16x8*)((char*)ws + (size_t)(cpy * CPY_V + fid * 64 + lane) * 16) = v;
    } else if (fid < 27) {                   // scaled biases, per copy
        const int Lb = fid - 24;
        float bv;
        if (Lb == 0)      bv = b1[lane];
        else if (Lb == 1) bv = b2[lane];
        else              bv = b3[lane];
        ws[cpy * CPY_F + 6144 + Lb * 64 + lane] = bv * SCALE;
    }
}

__global__ __launch_bounds__(BLK, 2) void globe_mfma(
    const float* __restrict__ pts, const float* __restrict__ ctr,
    const float* __restrict__ nrm, const float* __restrict__ areas,
    const float* __restrict__ rlen, const float* __restrict__ bout,
    const float* __restrict__ p_scale, const float* __restrict__ p_bias,
    const float* __restrict__ v_scale, const float* __restrict__ v_bias,
    const float* __restrict__ ws,
    float* __restrict__ out)
{
    // Per-wave slab: rows 0..63, cols 0..63 = activations (f16), cols 64..71 =
    // packed geometry (uint4/pair). 18432 B total -> 8 blocks/CU.
    __shared__ __align__(16) u16 hbuf[2][64][72];
    __shared__ float xr[4];

    const int tid  = threadIdx.x;
    const int lane = tid & 63;
    const int wv   = tid >> 6;
    const int l15  = lane & 15;
    const int q    = lane >> 4;
    const int t    = blockIdx.x;                     // both waves: same target

    const float px = pts[3 * t + 0], py = pts[3 * t + 1], pz = pts[3 * t + 2];
    const float invL0 = __builtin_amdgcn_rcpf(rlen[0]);
    const float invL1 = __builtin_amdgcn_rcpf(rlen[1]);
    f32x4 co_init = (f32x4){0.f, 0.f, 0.f, 0.f};
    if (q == 0) { co_init[0] = bout[0]; co_init[1] = bout[1]; co_init[2] = bout[2]; }

    u16 (*hb)[72] = hbuf[wv];
    const f16x8 fzero = (f16x8){0, 0, 0, 0, 0, 0, 0, 0};
    float accp = 0.f, avx = 0.f, avy = 0.f, avz = 0.f;

    #pragma unroll 1
    for (int ch = 0; ch < 4; ++ch) {
        // chunk-dependent weight copy: defeats LICM hoisting of frag loads
        const f16x8* __restrict__ wsFc = (const f16x8*)ws + ch * CPY_V;
        const float4* __restrict__ wsBc = (const float4*)(ws + ch * CPY_F + 6144);

        const int s = (wv * 4 + ch) * 64 + lane;
        // ---- per-pair geometry + features (lane = pair) ----
        const float cx = ctr[3 * s + 0], cy = ctr[3 * s + 1], cz = ctr[3 * s + 2];
        const float snx = nrm[3 * s + 0], sny = nrm[3 * s + 1], snz = nrm[3 * s + 2];
        const float ar = areas[s];
        const float rvx = px - cx, rvy = py - cy, rvz = pz - cz;
        const float r2 = rvx * rvx + rvy * rvy + rvz * rvz;
        const float r2e = r2 + 1e-8f;
        const float rinv = __builtin_amdgcn_rsqf(r2e);
        const float r = r2e * rinv;
        const float rhx = rvx * rinv, rhy = rvy * rinv, rhz = rvz * rinv;
        const float cth = rhx * snx + rhy * sny + rhz * snz;
        const float c2 = cth * cth;
        const float decay = ar * __builtin_amdgcn_rcpf(r2 + 1.0f);
        {
            f16x8 fv;
            fv[0] = (f16)(__builtin_amdgcn_rcpf(fmaf(r, invL0, 1.0f)));
            fv[1] = (f16)(__builtin_amdgcn_rcpf(fmaf(r, invL1, 1.0f)));
            fv[2] = (f16)1.0f;
            fv[3] = (f16)cth;
            fv[4] = (f16)fmaf(1.5f, c2, -0.5f);
            fv[5] = (f16)(cth * fmaf(2.5f, c2, -1.5f));
            fv[6] = (f16)__logf(ar);
            fv[7] = (f16)0.0f;
            *(f16x8*)&hb[lane][0] = fv;
        }
        {
            uint4 g;
            g.x = __builtin_bit_cast(u32, decay);
            g.y = __builtin_bit_cast(u32, __floats2half2_rn(rhx, rhy));
            g.z = __builtin_bit_cast(u32, __floats2half2_rn(rhz, snx));
            g.w = __builtin_bit_cast(u32, __floats2half2_rn(sny, snz));
            *(uint4*)&hb[lane][64] = g;   // dead pad cols of this pair's row
        }

        // ---- layer 1: stream w1 frags; K=32 with only k=0..7 live ----
        {
            const f16x8 a0 = wsFc[0 * 64 + lane];
            const f16x8 a1 = wsFc[1 * 64 + lane];
            const f16x8 a2 = wsFc[2 * 64 + lane];
            const f16x8 a3 = wsFc[3 * 64 + lane];
            #pragma unroll
            for (int n4 = 0; n4 < 4; ++n4) {
                const int row = n4 * 16 + l15;
                const f16x8 lv = *(const f16x8*)&hb[row][0];
                const f16x8 bf = (q == 0) ? lv : fzero;   // value select
                f32x4 c[4];
                #pragma unroll
                for (int mt = 0; mt < 4; ++mt) {
                    const float4 b = wsBc[0 * 16 + mt * 4 + q];
                    c[mt] = (f32x4){b.x, b.y, b.z, b.w};
                }
                c[0] = mfma16h(a0, bf, c[0]);
                c[1] = mfma16h(a1, bf, c[1]);
                c[2] = mfma16h(a2, bf, c[2]);
                c[3] = mfma16h(a3, bf, c[3]);
                #pragma unroll
                for (int mt = 0; mt < 4; ++mt)
                    store4h(&hb[row][mt * 16 + q * 4],
                            tanh_s(c[mt][0]), tanh_s(c[mt][1]),
                            tanh_s(c[mt][2]), tanh_s(c[mt][3]));
            }
        }

        // ---- layers 2 & 3: stream 8 frags per layer (transient regs) ----
        #pragma unroll
        for (int L = 0; L < 2; ++L) {
            const int fb = 4 + L * 8;
            const f16x8 a0 = wsFc[(fb + 0) * 64 + lane];
            const f16x8 a1 = wsFc[(fb + 1) * 64 + lane];
            const f16x8 a2 = wsFc[(fb + 2) * 64 + lane];
            const f16x8 a3 = wsFc[(fb + 3) * 64 + lane];
            const f16x8 a4 = wsFc[(fb + 4) * 64 + lane];
            const f16x8 a5 = wsFc[(fb + 5) * 64 + lane];
            const f16x8 a6 = wsFc[(fb + 6) * 64 + lane];
            const f16x8 a7 = wsFc[(fb + 7) * 64 + lane];
            #pragma unroll
            for (int n4 = 0; n4 < 4; ++n4) {
                const int row = n4 * 16 + l15;
                const f16x8 bfa = *(const f16x8*)&hb[row][q * 8];
                const f16x8 bfb = *(const f16x8*)&hb[row][32 + q * 8];
                f32x4 c[4];
                #pragma unroll
                for (int mt = 0; mt < 4; ++mt) {
                    const float4 b = wsBc[(L + 1) * 16 + mt * 4 + q];
                    c[mt] = (f32x4){b.x, b.y, b.z, b.w};
                }
                c[0] = mfma16h(a0, bfa, c[0]);
                c[1] = mfma16h(a1, bfa, c[1]);
                c[2] = mfma16h(a2, bfa, c[2]);
                c[3] = mfma16h(a3, bfa, c[3]);
                c[0] = mfma16h(a4, bfb, c[0]);
                c[1] = mfma16h(a5, bfb, c[1]);
                c[2] = mfma16h(a6, bfb, c[2]);
                c[3] = mfma16h(a7, bfb, c[3]);
                #pragma unroll
                for (int mt = 0; mt < 4; ++mt)
                    store4h(&hb[row][mt * 16 + q * 4],
                            tanh_s(c[mt][0]), tanh_s(c[mt][1]),
                            tanh_s(c[mt][2]), tanh_s(c[mt][3]));
            }
        }

        // ---- output layer (Wout hi/lo streamed) + accumulation ----
        {
            const f16x8 oh0 = wsFc[20 * 64 + lane];
            const f16x8 oh1 = wsFc[21 * 64 + lane];
            const f16x8 ol0 = wsFc[22 * 64 + lane];
            const f16x8 ol1 = wsFc[23 * 64 + lane];
            #pragma unroll
            for (int n4 = 0; n4 < 4; ++n4) {
                const int row = n4 * 16 + l15;
                const f16x8 bfa = *(const f16x8*)&hb[row][q * 8];
                const f16x8 bfb = *(const f16x8*)&hb[row][32 + q * 8];
                f32x4 co = co_init;
                co = mfma16h(oh0, bfa, co);
                co = mfma16h(ol0, bfa, co);
                co = mfma16h(oh1, bfb, co);
                co = mfma16h(ol1, bfb, co);
                if (q == 0) {   // C rows 0..2 = out channels, lanes 0..15
                    const uint4 g = *(const uint4*)&hb[row][64];
                    const float d = __builtin_bit_cast(float, g.x);
                    const float2 rxy = __half22float2(__builtin_bit_cast(__half2, g.y));
                    const float2 rzx = __half22float2(__builtin_bit_cast(__half2, g.z));
                    const float2 nyz = __half22float2(__builtin_bit_cast(__half2, g.w));
                    const float o0 = co[0], o1 = co[1], o2 = co[2];
                    accp = fmaf(o0, d, accp);
                    avx  = fmaf(fmaf(o1, rxy.x, o2 * rzx.y), d, avx);
                    avy  = fmaf(fmaf(o1, rxy.y, o2 * nyz.x), d, avy);
                    avz  = fmaf(fmaf(o1, rzx.x, o2 * nyz.y), d, avz);
                }
            }
        }
    }

    // ---- reduce across the 16 accumulating lanes ----
    #pragma unroll
    for (int off = 8; off > 0; off >>= 1) {
        accp += __shfl_down(accp, off);
        avx  += __shfl_down(avx,  off);
        avy  += __shfl_down(avy,  off);
        avz  += __shfl_down(avz,  off);
    }

    // ---- cross-wave combine ----
    if (wv == 1 && lane == 0) {
        xr[0] = accp; xr[1] = avx; xr[2] = avy; xr[3] = avz;
    }
    __syncthreads();
    if (wv == 0 && lane == 0) {
        accp += xr[0]; avx += xr[1]; avy += xr[2]; avz += xr[3];
        const float ps = p_scale[0], pb = p_bias[0];
        const float vs = v_scale[0], vb = v_bias[0];
        out[4 * t + 0] = fmaf(accp, ps, pb);
        out[4 * t + 1] = fmaf(avx, vs, vb);
        out[4 * t + 2] = fmaf(avy, vs, vb);
        out[4 * t + 3] = fmaf(avz, vs, vb);
    }
}

extern "C" void kernel_launch(void* const* d_in, const int* in_sizes, int n_in,
                              void* d_out, int out_size, void* d_ws, size_t ws_size,
                              hipStream_t stream) {
    (void)in_sizes; (void)n_in; (void)ws_size; (void)out_size;
    const float* pts   = (const float*)d_in[0];
    const float* ctr   = (const float*)d_in[1];
    const float* nrm   = (const float*)d_in[2];
    const float* areas = (const float*)d_in[3];
    const float* rlen  = (const float*)d_in[4];
    const float* W1    = (const float*)d_in[5];
    const float* b1    = (const float*)d_in[6];
    const float* W2    = (const float*)d_in[7];
    const float* b2    = (const float*)d_in[8];
    const float* W3    = (const float*)d_in[9];
    const float* b3    = (const float*)d_in[10];
    const float* Wout  = (const float*)d_in[11];
    const float* bout  = (const float*)d_in[12];
    const float* ps    = (const float*)d_in[13];
    const float* pb    = (const float*)d_in[14];
    const float* vs    = (const float*)d_in[15];
    const float* vb    = (const float*)d_in[16];
    float* ws = (float*)d_ws;

    prep_kernel<<<28, 256, 0, stream>>>(W1, b1, W2, b2, W3, b3, Wout, ws);
    globe_mfma<<<N_T, BLK, 0, stream>>>(
        pts, ctr, nrm, areas, rlen, bout, ps, pb, vs, vb, ws, (float*)d_out);
}